// Round 8
// baseline (274.267 us; speedup 1.0000x reference)
//
#include <hip/hip_runtime.h>

#define NN 100000
#define NE 1600000
#define D  64
#define BSH 8                                  // bucket shift: 256 nodes/bucket
#define NBKT ((NN + 255) >> BSH)               // 391
#define NBLK_E ((NE / 4 + 1023) / 1024)        // 391 blocks, 1024 int4s each
#define H_SCALE 256.0f
#define H_ISCALE 0.00390625f

typedef __attribute__((ext_vector_type(8))) short short8v;
typedef __attribute__((ext_vector_type(4))) unsigned short ushort4v;
typedef __attribute__((ext_vector_type(4))) float f32x4;
typedef __attribute__((ext_vector_type(2))) float f32x2;

__device__ __forceinline__ float bf2f(unsigned short x) {
    return __uint_as_float(((unsigned)x) << 16);
}
__device__ __forceinline__ unsigned short f2bf(float f) {  // RNE
    unsigned u = __float_as_uint(f);
    return (unsigned short)((u + 0x7fff + ((u >> 16) & 1)) >> 16);
}

// ---- zero ghist ----
__global__ void k_zero(int* __restrict__ g) {
    int i = blockIdx.x * 256 + threadIdx.x;
    if (i < NBKT) g[i] = 0;
}

// ---- pass A: global bucket histogram (LDS-staged) ----
__global__ __launch_bounds__(256) void k_hist(const int* __restrict__ row,
                                              int* __restrict__ ghist) {
    __shared__ int h[NBKT];
    int tid = threadIdx.x;
    for (int i = tid; i < NBKT; i += 256) h[i] = 0;
    __syncthreads();
    int base4 = blockIdx.x * 1024;
    #pragma unroll
    for (int k = 0; k < 4; ++k) {
        int i4 = base4 + k * 256 + tid;
        if (i4 < NE / 4) {
            int4 r = ((const int4*)row)[i4];
            atomicAdd(&h[r.x >> BSH], 1);
            atomicAdd(&h[r.y >> BSH], 1);
            atomicAdd(&h[r.z >> BSH], 1);
            atomicAdd(&h[r.w >> BSH], 1);
        }
    }
    __syncthreads();
    for (int i = tid; i < NBKT; i += 256) if (h[i]) atomicAdd(&ghist[i], h[i]);
}

// ---- pass B: exclusive scan of 391 bucket counts (1 block) ----
__global__ __launch_bounds__(256) void k_bscan(const int* __restrict__ ghist,
                                               int* __restrict__ bbase,
                                               int* __restrict__ bcur) {
    __shared__ int sc[2][512];
    int t = threadIdx.x;
    int cur = 0;
    #pragma unroll
    for (int k = 0; k < 2; ++k) {
        int i = t + k * 256;
        sc[0][i] = (i < NBKT) ? ghist[i] : 0;
    }
    __syncthreads();
    for (int s = 1; s < 512; s <<= 1) {
        #pragma unroll
        for (int k = 0; k < 2; ++k) {
            int i = t + k * 256;
            sc[cur ^ 1][i] = sc[cur][i] + ((i >= s) ? sc[cur][i - s] : 0);
        }
        cur ^= 1;
        __syncthreads();
    }
    #pragma unroll
    for (int k = 0; k < 2; ++k) {
        int i = t + k * 256;
        if (i < NBKT) {
            int b = (i == 0) ? 0 : sc[cur][i - 1];
            bbase[i] = b;
            bcur[i] = b;
        } else if (i == NBKT) {
            bbase[NBKT] = sc[cur][NBKT - 1];   // = NE
        }
    }
}

// ---- pass C: bucket-sort edges into packed u32 (lrow<<17 | col) ----
__global__ __launch_bounds__(256) void k_bucket(const int* __restrict__ row,
                                                const int* __restrict__ col,
                                                int* __restrict__ bcur,
                                                unsigned* __restrict__ sorted) {
    __shared__ int hist[NBKT];
    __shared__ int bbase_s[NBKT];
    int tid = threadIdx.x;
    for (int i = tid; i < NBKT; i += 256) hist[i] = 0;
    __syncthreads();
    int base4 = blockIdx.x * 1024;
    int4 r4[4], c4[4];
    int rank[16];
    bool valid[4];
    #pragma unroll
    for (int k = 0; k < 4; ++k) {
        int i4 = base4 + k * 256 + tid;
        valid[k] = (i4 < NE / 4);
        if (valid[k]) {
            r4[k] = ((const int4*)row)[i4];
            c4[k] = ((const int4*)col)[i4];
            rank[k * 4 + 0] = atomicAdd(&hist[r4[k].x >> BSH], 1);
            rank[k * 4 + 1] = atomicAdd(&hist[r4[k].y >> BSH], 1);
            rank[k * 4 + 2] = atomicAdd(&hist[r4[k].z >> BSH], 1);
            rank[k * 4 + 3] = atomicAdd(&hist[r4[k].w >> BSH], 1);
        }
    }
    __syncthreads();
    for (int i = tid; i < NBKT; i += 256)
        bbase_s[i] = hist[i] ? atomicAdd(&bcur[i], hist[i]) : 0;
    __syncthreads();
    #pragma unroll
    for (int k = 0; k < 4; ++k) {
        if (valid[k]) {
            int rr[4] = {r4[k].x, r4[k].y, r4[k].z, r4[k].w};
            int cc[4] = {c4[k].x, c4[k].y, c4[k].z, c4[k].w};
            #pragma unroll
            for (int j = 0; j < 4; ++j) {
                int b = rr[j] >> BSH;
                unsigned pk = ((unsigned)(rr[j] & 255) << 17) | (unsigned)cc[j];
                sorted[bbase_s[b] + rank[k * 4 + j]] = pk;
            }
        }
    }
}

// ---- pass D: per-bucket fine CSR (LDS count -> scan -> scatter) ----
__global__ __launch_bounds__(256) void k_fine(const unsigned* __restrict__ sorted,
                                              const int* __restrict__ bbase,
                                              int* __restrict__ csr_col,
                                              int* __restrict__ cnt_g,
                                              int2* __restrict__ se_g) {
    __shared__ int cnt_s[256];
    __shared__ int cur_s[256];
    __shared__ int sc[2][256];
    int b = blockIdx.x;
    int tid = threadIdx.x;
    int s0 = bbase[b], e0 = bbase[b + 1];
    cnt_s[tid] = 0;
    __syncthreads();
    for (int i = s0 + tid; i < e0; i += 256)
        atomicAdd(&cnt_s[sorted[i] >> 17], 1);
    __syncthreads();
    int cur = 0;
    sc[0][tid] = cnt_s[tid];
    __syncthreads();
    for (int s = 1; s < 256; s <<= 1) {
        sc[cur ^ 1][tid] = sc[cur][tid] + ((tid >= s) ? sc[cur][tid - s] : 0);
        cur ^= 1;
        __syncthreads();
    }
    int incl = sc[cur][tid];
    cur_s[tid] = incl - cnt_s[tid];           // exclusive offset
    int nb = NN - b * 256;
    nb = nb > 256 ? 256 : nb;
    if (tid < nb) {
        int node = b * 256 + tid;
        cnt_g[node] = cnt_s[tid];
        se_g[node] = make_int2(s0 + incl - cnt_s[tid], s0 + incl);
    }
    __syncthreads();
    for (int i = s0 + tid; i < e0; i += 256) {
        unsigned u = sorted[i];
        int p = atomicAdd(&cur_s[u >> 17], 1);
        csr_col[s0 + p] = (int)(u & 0x1FFFFu);
    }
}

// ---- c[o] = sum_k W3[o][k] * relu(W4[k]) ----
__global__ void k_cvec(const float* __restrict__ W3, const float* __restrict__ W4,
                       float* __restrict__ c) {
    int o = threadIdx.x;  // 64 threads
    float s = 0.f;
    for (int k = 0; k < D; ++k) {
        float w4 = W4[k];
        s += W3[o * D + k] * (w4 > 0.f ? w4 : 0.f);
    }
    c[o] = s;
}

// ---- W1, W2 fp32 -> bf16 ----
__global__ void k_wprep(const float* __restrict__ W1, const float* __restrict__ W2,
                        unsigned short* __restrict__ w1b, unsigned short* __restrict__ w2b) {
    int i = blockIdx.x * 256 + threadIdx.x;
    if (i < D * D) {
        w1b[i] = f2bf(W1[i]);
        w2b[i] = f2bf(W2[i]);
    }
}

// ---- base_bf = bf16(Xv@W1.T + deg*c) via MFMA; emb_bf = bf16(relu(.)) ----
__global__ __launch_bounds__(256) void k_base(
        const float* __restrict__ Xv, const unsigned short* __restrict__ w1b,
        const int* __restrict__ cnt, const float* __restrict__ cvec,
        unsigned short* __restrict__ base_bf, unsigned short* __restrict__ emb_bf) {
    int wid = blockIdx.x * 4 + (threadIdx.x >> 6);
    int lane = threadIdx.x & 63;
    int m0 = wid * 16;
    if (m0 >= NN) return;
    int r = lane & 15, half = lane >> 4;
    const float* arow = Xv + (size_t)(m0 + r) * D + half * 8;
    f32x4 xa = *(const f32x4*)(arow);
    f32x4 xb = *(const f32x4*)(arow + 4);
    f32x4 xc = *(const f32x4*)(arow + 32);
    f32x4 xd = *(const f32x4*)(arow + 36);
    short8v a0, a1;
    #pragma unroll
    for (int j = 0; j < 4; ++j) {
        a0[j]     = (short)f2bf(xa[j]);
        a0[j + 4] = (short)f2bf(xb[j]);
        a1[j]     = (short)f2bf(xc[j]);
        a1[j + 4] = (short)f2bf(xd[j]);
    }
    int4 c4 = *(const int4*)(cnt + m0 + half * 4);    // deg of the 4 C-rows this lane holds
    float dg[4] = {(float)c4.x, (float)c4.y, (float)c4.z, (float)c4.w};
    #pragma unroll
    for (int t = 0; t < 4; ++t) {
        short8v b0 = *(const short8v*)(w1b + (size_t)(t * 16 + r) * D + half * 8);
        short8v b1 = *(const short8v*)(w1b + (size_t)(t * 16 + r) * D + 32 + half * 8);
        f32x4 cacc = {0.f, 0.f, 0.f, 0.f};
        cacc = __builtin_amdgcn_mfma_f32_16x16x32_bf16(a0, b0, cacc, 0, 0, 0);
        cacc = __builtin_amdgcn_mfma_f32_16x16x32_bf16(a1, b1, cacc, 0, 0, 0);
        float cv = cvec[t * 16 + r];
        #pragma unroll
        for (int q = 0; q < 4; ++q) {
            float s = cacc[q] + dg[q] * cv;
            size_t idx = (size_t)(m0 + half * 4 + q) * D + t * 16 + r;
            base_bf[idx] = f2bf(s);
            emb_bf[idx] = f2bf(s > 0.f ? s : 0.f);
        }
    }
}

// ---- h8 = fp8_e4m3( (emb_bf @ W2bf.T) * H_SCALE ) via MFMA, 16 nodes/wave ----
__global__ __launch_bounds__(256) void k_h(
        const unsigned short* __restrict__ emb_bf, const unsigned short* __restrict__ w2b,
        unsigned char* __restrict__ h8) {
    int wid = blockIdx.x * 4 + (threadIdx.x >> 6);
    int lane = threadIdx.x & 63;
    int m0 = wid * 16;
    if (m0 >= NN) return;
    int r = lane & 15, half = lane >> 4;
    const unsigned short* arow = emb_bf + (size_t)(m0 + r) * D + half * 8;
    short8v a0 = *(const short8v*)(arow);
    short8v a1 = *(const short8v*)(arow + 32);
    #pragma unroll
    for (int t = 0; t < 4; ++t) {
        short8v b0 = *(const short8v*)(w2b + (size_t)(t * 16 + r) * D + half * 8);
        short8v b1 = *(const short8v*)(w2b + (size_t)(t * 16 + r) * D + 32 + half * 8);
        f32x4 cacc = {0.f, 0.f, 0.f, 0.f};
        cacc = __builtin_amdgcn_mfma_f32_16x16x32_bf16(a0, b0, cacc, 0, 0, 0);
        cacc = __builtin_amdgcn_mfma_f32_16x16x32_bf16(a1, b1, cacc, 0, 0, 0);
        #pragma unroll
        for (int q = 0; q < 4; ++q) {
            int pk = __builtin_amdgcn_cvt_pk_fp8_f32(cacc[q] * H_SCALE, 0.f, 0, false);
            h8[(size_t)(m0 + half * 4 + q) * D + t * 16 + r] = (unsigned char)(pk & 0xff);
        }
    }
}

// ---- decode+accumulate 8 fp8 from a uint2 (identical to round-6 inline pattern) ----
__device__ __forceinline__ void acc8(float* acc, const uint2& v) {
    f32x2 f;
    f = __builtin_amdgcn_cvt_pk_f32_fp8(v.x, false); acc[0] += f.x; acc[1] += f.y;
    f = __builtin_amdgcn_cvt_pk_f32_fp8(v.x, true);  acc[2] += f.x; acc[3] += f.y;
    f = __builtin_amdgcn_cvt_pk_f32_fp8(v.y, false); acc[4] += f.x; acc[5] += f.y;
    f = __builtin_amdgcn_cvt_pk_f32_fp8(v.y, true);  acc[6] += f.x; acc[7] += f.y;
}

// ---- emb[i] = relu(base[i] + (1/S) * sum_{j in N(i)} h8[csr_col[j]]) ----
// Round-6 structure (8 groups x 8 lanes, uint2, butterfly, g<2 epilogue) with
// uniform-exec index prefetch: 1 coalesced idx load + 8 wave-uniform shfl
// broadcasts + 8 predicated gathers (all independent -> ~16 loads in flight).
template<int LAST>
__global__ __launch_bounds__(256) void k_pull(
        const int2* __restrict__ se_g,
        const int* __restrict__ csr_col, const unsigned char* __restrict__ h8,
        const unsigned short* __restrict__ base_bf,
        unsigned short* __restrict__ out_bf, float* __restrict__ out_f32) {
    int tid = threadIdx.x;
    int wave = tid >> 6, lane = tid & 63;
    int g = lane >> 3, l = lane & 7;   // group g: edges e == g (mod 8); lane: ch l*8..+7
    for (int it = blockIdx.x; it < NN / 4; it += gridDim.x) {
        int node = it * 4 + wave;
        int2 se = se_g[node];
        int start = se.x, deg = se.y - se.x;
        // coalesced prefetch of up to 64 edge indices (deg <= 64 in practice)
        int idx = (lane < deg) ? csr_col[start + lane] : 0;
        // broadcast: executed by ALL lanes, no divergence around shfl
        int cc[8];
        #pragma unroll
        for (int k = 0; k < 8; ++k) cc[k] = __shfl(idx, g + 8 * k);
        float acc[8] = {0.f, 0.f, 0.f, 0.f, 0.f, 0.f, 0.f, 0.f};
        #pragma unroll
        for (int k = 0; k < 8; ++k) {
            if (g + 8 * k < deg) {
                uint2 v = *((const uint2*)(h8 + (size_t)cc[k] * D) + l);
                acc8(acc, v);
            }
        }
        for (int e = 64 + g; e < deg; e += 8) {   // cold tail (deg>64: ~never)
            uint2 v = *((const uint2*)(h8 + (size_t)csr_col[start + e] * D) + l);
            acc8(acc, v);
        }
        // butterfly over the 8 groups (lane bits 3,4,5) — round-6 verbatim
        #pragma unroll
        for (int m = 8; m < 64; m <<= 1) {
            #pragma unroll
            for (int u = 0; u < 8; ++u) acc[u] += __shfl_xor(acc[u], m);
        }
        if (g < 2) {     // 16 lanes store one coalesced row — round-6 verbatim
            int off = l * 8 + g * 4;
            ushort4v b4 = *(const ushort4v*)(base_bf + (size_t)node * D + off);
            float rr[4];
            #pragma unroll
            for (int u = 0; u < 4; ++u) {
                float a = (g == 1) ? acc[u + 4] : acc[u];
                rr[u] = fmaxf(fmaf(a, H_ISCALE, bf2f(b4[u])), 0.f);
            }
            if (LAST) {
                f32x4 o4 = {rr[0], rr[1], rr[2], rr[3]};
                *(f32x4*)(out_f32 + (size_t)node * D + off) = o4;
            } else {
                ushort4v o4;
                #pragma unroll
                for (int u = 0; u < 4; ++u) o4[u] = f2bf(rr[u]);
                *(ushort4v*)(out_bf + (size_t)node * D + off) = o4;
            }
        }
    }
}

extern "C" void kernel_launch(void* const* d_in, const int* in_sizes, int n_in,
                              void* d_out, int out_size, void* d_ws, size_t ws_size,
                              hipStream_t stream) {
    const float* Xv = (const float*)d_in[0];
    const int*   ei = (const int*)d_in[1];
    const float* W1 = (const float*)d_in[2];
    const float* W2 = (const float*)d_in[3];
    const float* W3 = (const float*)d_in[4];
    const float* W4 = (const float*)d_in[5];

    char* ws = (char*)d_ws;
    size_t off = 0;
    unsigned short* base_bf = (unsigned short*)(ws + off); off += (size_t)NN * D * 2; // 12.8 MB
    unsigned char* h8 = (unsigned char*)(ws + off);    off += (size_t)NN * D;      // 6.4 MB
    int* csr_col = (int*)(ws + off);                   off += (size_t)NE * 4;      // 6.4 MB
    int* cnt     = (int*)(ws + off);                   off += (size_t)NN * 4;
    int2* se_g   = (int2*)(ws + off);                  off += (size_t)NN * 8;
    int* ghist   = (int*)(ws + off);                   off += NBKT * 4;
    int* bbase   = (int*)(ws + off);                   off += (NBKT + 1) * 4;
    int* bcur    = (int*)(ws + off);                   off += NBKT * 4;
    float* cvec  = (float*)(ws + off);                 off += D * 4;
    unsigned short* w1b = (unsigned short*)(ws + off); off += D * D * 2;
    unsigned short* w2b = (unsigned short*)(ws + off); off += D * D * 2;
    unsigned* sorted = (unsigned*)(ws + off);          off += (size_t)NE * 4;      // 6.4 MB

    // intermediate bf16 emb lives in d_out's bytes (final step overwrites with fp32)
    unsigned short* emb_bf = (unsigned short*)d_out;
    float* emb_f32 = (float*)d_out;

    const int* row = ei;
    const int* col = ei + NE;

    // ---- CSR build: two-level multisplit (dense writes) ----
    k_zero<<<2, 256, 0, stream>>>(ghist);
    k_hist<<<NBLK_E, 256, 0, stream>>>(row, ghist);
    k_bscan<<<1, 256, 0, stream>>>(ghist, bbase, bcur);
    k_bucket<<<NBLK_E, 256, 0, stream>>>(row, col, bcur, sorted);
    k_fine<<<NBKT, 256, 0, stream>>>(sorted, bbase, csr_col, cnt, se_g);

    // ---- weights prep + base, emb1 = relu(base) ----
    k_cvec<<<1, 64, 0, stream>>>(W3, W4, cvec);
    k_wprep<<<16, 256, 0, stream>>>(W1, W2, w1b, w2b);
    k_base<<<(NN / 16 + 3) / 4, 256, 0, stream>>>(Xv, w1b, cnt, cvec, base_bf, emb_bf);

    // ---- 3 remaining message-passing steps ----
    for (int t = 0; t < 3; ++t) {
        k_h<<<(NN / 16 + 3) / 4, 256, 0, stream>>>(emb_bf, w2b, h8);
        if (t < 2)
            k_pull<0><<<2500, 256, 0, stream>>>(se_g, csr_col, h8, base_bf, emb_bf, nullptr);
        else
            k_pull<1><<<2500, 256, 0, stream>>>(se_g, csr_col, h8, base_bf, nullptr, emb_f32);
    }
}